// Round 3
// baseline (1067.188 us; speedup 1.0000x reference)
//
#include <hip/hip_runtime.h>
#include <cstdint>

typedef __attribute__((ext_vector_type(8))) short short8;
typedef __attribute__((ext_vector_type(4))) float v4f;

#define B_ 4
#define C_ 128
#define K_ 64
#define H_ 256
#define W_ 256
#define HW_ (H_*W_)
#define L_ 1024
#define J_ 256
#define NCH 8   // 64-l chunks per half-block

// ws byte offsets
#define OFF_WFH  0ull
#define OFF_WFL  131072ull
#define OFF_WOF  262144ull
#define OFF_BIAS 327680ull
#define OFF_CTR  329728ull
#define OFF_VWS  335872ull
#define OFF_UWS  (OFF_VWS + 33554432ull)   // 256 j * 16384 f32 = 16.8 MB

static __device__ __forceinline__ unsigned short f2bf(float x) {
    unsigned u = __builtin_bit_cast(unsigned, x);
    unsigned r = (u + 0x7FFFu + ((u >> 16) & 1u)) >> 16;
    return (unsigned short)r;
}
static __device__ __forceinline__ float bf2f(unsigned short h) {
    unsigned u = ((unsigned)h) << 16;
    return __builtin_bit_cast(float, u);
}
static __device__ __forceinline__ v4f mfma16(short8 a, short8 b, v4f c) {
    return __builtin_amdgcn_mfma_f32_16x16x32_bf16(a, b, c, 0, 0, 0);
}

union U8 { unsigned short u[8]; short8 v; };

// ---------------- prep: pack weights + zero U/ctr ----------------
__global__ void prep_kernel(const float* __restrict__ w_v, const float* __restrict__ b_v,
                            const float* __restrict__ w1_1, const float* __restrict__ b1_1,
                            const float* __restrict__ w2_1, const float* __restrict__ b2_1,
                            const float* __restrict__ wout1,
                            const float* __restrict__ w1_2, const float* __restrict__ b1_2,
                            const float* __restrict__ w2_2, const float* __restrict__ b2_2,
                            const float* __restrict__ wout2,
                            char* __restrict__ wsb) {
    int tid = blockIdx.x * 256 + threadIdx.x;
    if (tid < 65536) {
        // proj weights: [s][omt 16][kc 4][lane 64][jj 8], rows o: w1(128), w2(64), wv-half(64)
        int jj = tid & 7, lane = (tid >> 3) & 63, kc = (tid >> 9) & 3;
        int omt = (tid >> 11) & 15, s = (tid >> 15) & 1;
        int o = omt * 16 + (lane & 15);
        int c = kc * 32 + ((lane >> 4) * 8) + jj;
        const float* w1 = s ? w1_2 : w1_1;
        const float* w2 = s ? w2_2 : w2_1;
        float v;
        if (o < 128)      v = w1[o * 128 + c];
        else if (o < 192) v = w2[(o - 128) * 128 + c];
        else              v = w_v[(o - 192) * 256 + s * 128 + c];
        unsigned short hi = f2bf(v);
        unsigned short lo = f2bf(v - bf2f(hi));
        ((unsigned short*)(wsb + OFF_WFH))[tid] = hi;
        ((unsigned short*)(wsb + OFF_WFL))[tid] = lo;
    } else if (tid < 98304) {
        int id = tid - 65536;
        int jj = id & 7, lane = (id >> 3) & 63, kc = (id >> 9) & 3;
        int om = (id >> 11) & 7, s = (id >> 14) & 1;
        int o = om * 16 + (lane & 15);
        int c = kc * 32 + ((lane >> 4) * 8) + jj;
        const float* wo = s ? wout2 : wout1;
        ((unsigned short*)(wsb + OFF_WOF))[id] = f2bf(wo[o * 128 + c]);
    } else if (tid < 98816) {
        int id = tid - 98304;
        int s = id >> 8, o = id & 255;
        const float* b1 = s ? b1_2 : b1_1;
        const float* b2 = s ? b2_2 : b2_1;
        float v;
        if (o < 128)      v = b1[o];
        else if (o < 192) v = b2[o - 128];
        else              v = b_v[o - 192];
        ((float*)(wsb + OFF_BIAS))[id] = v;
    } else if (tid < 99072) {
        ((int*)(wsb + OFF_CTR))[tid - 98816] = 0;
    }
    // zero partial-U accumulators (16.8 MB)
    float* uz = (float*)(wsb + OFF_UWS);
    for (unsigned i = tid; i < 1048576u; i += 102400u)
        *(v4f*)&uz[i * 4] = (v4f){0.f, 0.f, 0.f, 0.f};
}

// ---------------- fused half-j kernel (split-K over l; last block does epilogue) ---
// grid 512: j = bid & 255, half = bid >> 8  (pairs land on the same XCD)
// waves 0-3: Y1 rows (c 0..127); waves 4-5: Y2 rows (k 0..63); waves 6-7: V logits
__global__ __attribute__((amdgpu_flat_work_group_size(512, 512), amdgpu_waves_per_eu(4, 4)))
void fused_kernel(
    const float* __restrict__ x1, const float* __restrict__ x2,
    char* __restrict__ wsb, float* __restrict__ out) {
    // LDS 77056 B -> 2 blocks/CU
    __shared__ __align__(16) char smem[77056];
    unsigned short* Xfh = (unsigned short*)&smem[0];       // [ln4][kc4][lane64][8]
    unsigned short* Xfl = (unsigned short*)&smem[16384];
    unsigned short* Y1b = (unsigned short*)&smem[32768];   // [128 c][72 l] bf16
    unsigned short* Y2b = (unsigned short*)&smem[51200];   // [64 k][72 l] bf16
    float*          LG  = (float*)&smem[60416];            // [64 l][65 k] fp32
    float*          UF  = (float*)&smem[0];                // [64 k][133 c] fp32 (epilogue)
    unsigned short* UH  = (unsigned short*)&smem[51200];   // [64 k][136 c] bf16 (epilogue)
    unsigned short* MB  = (unsigned short*)&smem[0];       // [128 o][72 k] bf16 (epilogue)
    __shared__ int winflag;

    const unsigned short* wfh = (const unsigned short*)(wsb + OFF_WFH);
    const unsigned short* wfl = (const unsigned short*)(wsb + OFF_WFL);
    const unsigned short* wof = (const unsigned short*)(wsb + OFF_WOF);
    const float* biasws = (const float*)(wsb + OFF_BIAS);
    unsigned short* vws = (unsigned short*)(wsb + OFF_VWS);
    float* Uws = (float*)(wsb + OFF_UWS);

    const int t = threadIdx.x;
    const int lane = t & 63;
    const int w = __builtin_amdgcn_readfirstlane(t >> 6);
    const int j = blockIdx.x & 255;
    const int half = blockIdx.x >> 8;
    const int b = j >> 6, q = j & 63, i0 = q >> 3, i2 = q & 7;
    const long imgbase = (long)b * C_ * HW_ + (long)(i0 * 32) * W_ + i2 * 32;

    const int lquad = lane >> 4;        // 0..3
    const int lmod = lane & 15;

    // biases per lane (rows o = w*32 + h*16 + lquad*4 + r)
    float pb[2][2][4];
#pragma unroll
    for (int s = 0; s < 2; s++)
#pragma unroll
        for (int h = 0; h < 2; h++)
#pragma unroll
            for (int r = 0; r < 4; r++)
                pb[s][h][r] = biasws[s * 256 + w * 32 + h * 16 + lquad * 4 + r];

    v4f uacc[2][4];
#pragma unroll
    for (int s = 0; s < 2; s++)
#pragma unroll
        for (int kn = 0; kn < 4; kn++)
            uacc[s][kn] = (v4f){0.f, 0.f, 0.f, 0.f};

    // staging decode: thread t stages l-column ll, c-octets {cw, cw+8}
    const int ll = t & 63;              // l within 64-chunk
    const int cw = t >> 6;              // 0..7
    const int lgrp = ll >> 4, lp = ll & 15;

    // prefetch first chunk (lc=0, s=0) into registers
    float R[16];
#pragma unroll
    for (int p = 0; p < 2; p++)
#pragma unroll
        for (int jj = 0; jj < 8; jj++) {
            int c = (p * 8 + cw) * 8 + jj;
            R[p * 8 + jj] = x1[imgbase + (long)c * HW_ + (half * 16 + (ll >> 5)) * W_ + (ll & 31)];
        }

    for (int lc = 0; lc < NCH; lc++) {
        v4f pacc[2][4];
#pragma unroll
        for (int s = 0; s < 2; s++) {
            // ---- convert prefetched R (fp32 -> bf16 hi/lo, B-frag order) into LDS ----
#pragma unroll
            for (int p = 0; p < 2; p++) {
                U8 hv, lv;
#pragma unroll
                for (int jj = 0; jj < 8; jj++) {
                    float v = R[p * 8 + jj];
                    unsigned short hh = f2bf(v);
                    hv.u[jj] = hh;
                    lv.u[jj] = f2bf(v - bf2f(hh));
                }
                int co = p * 8 + cw;
                int base = ((lgrp * 4 + (co >> 2)) * 64 + ((co & 3) * 16 + lp)) * 8;
                *(short8*)&Xfh[base] = hv.v;
                *(short8*)&Xfl[base] = lv.v;
            }
            __syncthreads();
            // ---- issue next-stage x loads; they ride under the MFMA phase ----
            if (s == 0 || lc < NCH - 1) {
                const float* xp = s ? x1 : x2;
                const int nrow = half * 16 + (s ? (lc + 1) : lc) * 2 + (ll >> 5);
#pragma unroll
                for (int p = 0; p < 2; p++)
#pragma unroll
                    for (int jj = 0; jj < 8; jj++) {
                        int c = (p * 8 + cw) * 8 + jj;
                        R[p * 8 + jj] = xp[imgbase + (long)c * HW_ + (long)nrow * W_ + (ll & 31)];
                    }
            }
            // ---- projection MFMAs (split-3: Whi*Xhi + Wlo*Xhi + Whi*Xlo) ----
            if (s == 0 || w < 6) {
#pragma unroll
                for (int h = 0; h < 2; h++)
#pragma unroll
                    for (int ln = 0; ln < 4; ln++)
                        pacc[h][ln] = (v4f){pb[s][h][0], pb[s][h][1], pb[s][h][2], pb[s][h][3]};
            }
#pragma unroll
            for (int kc = 0; kc < 4; kc++) {
                int wi0 = (((s * 16 + (w * 2 + 0)) * 4 + kc) * 64 + lane) * 8;
                int wi1 = (((s * 16 + (w * 2 + 1)) * 4 + kc) * 64 + lane) * 8;
                short8 wh0 = *(const short8*)&wfh[wi0];
                short8 wh1 = *(const short8*)&wfh[wi1];
                short8 wlo0 = *(const short8*)&wfl[wi0];
                short8 wlo1 = *(const short8*)&wfl[wi1];
#pragma unroll
                for (int ln = 0; ln < 4; ln++) {
                    short8 bh = *(const short8*)&Xfh[((ln * 4 + kc) * 64 + lane) * 8];
                    short8 bl = *(const short8*)&Xfl[((ln * 4 + kc) * 64 + lane) * 8];
                    pacc[0][ln] = mfma16(wh0, bh, pacc[0][ln]);
                    pacc[0][ln] = mfma16(wlo0, bh, pacc[0][ln]);
                    pacc[0][ln] = mfma16(wh0, bl, pacc[0][ln]);
                    pacc[1][ln] = mfma16(wh1, bh, pacc[1][ln]);
                    pacc[1][ln] = mfma16(wlo1, bh, pacc[1][ln]);
                    pacc[1][ln] = mfma16(wh1, bl, pacc[1][ln]);
                }
            }
            // ---- write Y / logits ----
            if (w < 4) {
#pragma unroll
                for (int h = 0; h < 2; h++)
#pragma unroll
                    for (int ln = 0; ln < 4; ln++)
#pragma unroll
                        for (int r = 0; r < 4; r++)
                            Y1b[(w * 32 + h * 16 + lquad * 4 + r) * 72 + ln * 16 + lmod] = f2bf(pacc[h][ln][r]);
            } else if (w < 6) {
#pragma unroll
                for (int h = 0; h < 2; h++)
#pragma unroll
                    for (int ln = 0; ln < 4; ln++)
#pragma unroll
                        for (int r = 0; r < 4; r++)
                            Y2b[((w - 4) * 32 + h * 16 + lquad * 4 + r) * 72 + ln * 16 + lmod] = f2bf(pacc[h][ln][r]);
            } else if (s == 1) {
#pragma unroll
                for (int h = 0; h < 2; h++)
#pragma unroll
                    for (int ln = 0; ln < 4; ln++)
#pragma unroll
                        for (int r = 0; r < 4; r++)
                            LG[(ln * 16 + lmod) * 65 + (w - 6) * 32 + h * 16 + lquad * 4 + r] = pacc[h][ln][r];
            }
            __syncthreads();
            // ---- U-MFMA: U_s += Y1 @ Y2^T over this 64-l chunk ----
#pragma unroll
            for (int kcl = 0; kcl < 2; kcl++) {
                short8 a = *(const short8*)&Y1b[(w * 16 + lmod) * 72 + kcl * 32 + lquad * 8];
#pragma unroll
                for (int kn = 0; kn < 4; kn++) {
                    short8 bb = *(const short8*)&Y2b[(kn * 16 + lmod) * 72 + kcl * 32 + lquad * 8];
                    uacc[s][kn] = mfma16(a, bb, uacc[s][kn]);
                }
            }
            if (s == 1) {
                // ---- wave-parallel softmax + direct V store (all 512 threads) ----
                // 8 threads per l-column: part = t&7 owns k in [part*8, part*8+8)
                int l2 = t >> 3, part = t & 7;
                float vv[8];
#pragma unroll
                for (int i = 0; i < 8; i++) vv[i] = LG[l2 * 65 + part * 8 + i];
                float mx = vv[0];
#pragma unroll
                for (int i = 1; i < 8; i++) mx = fmaxf(mx, vv[i]);
                mx = fmaxf(mx, __shfl_xor(mx, 1));
                mx = fmaxf(mx, __shfl_xor(mx, 2));
                mx = fmaxf(mx, __shfl_xor(mx, 4));
                float ssum = 0.f;
#pragma unroll
                for (int i = 0; i < 8; i++) { float e = __expf(vv[i] - mx); vv[i] = e; ssum += e; }
                ssum += __shfl_xor(ssum, 1);
                ssum += __shfl_xor(ssum, 2);
                ssum += __shfl_xor(ssum, 4);
                float rs = 1.f / ssum;
                U8 o1;
#pragma unroll
                for (int i = 0; i < 8; i++) o1.u[i] = f2bf(vv[i] * rs);
                unsigned long long vb = ((unsigned long long)j * 1024 + half * 512 + lc * 64 + l2) * 64 + part * 8;
                *(short8*)&vws[vb] = o1.v;
            }
        }
    }

    // ---------------- split-K combine: atomicAdd partial U, last block wins -------
    {
        float* up = &Uws[(unsigned)j * 16384u];
#pragma unroll
        for (int s = 0; s < 2; s++)
#pragma unroll
            for (int kn = 0; kn < 4; kn++) {
                int base = (((s * 8 + w) * 4 + kn) * 64 + lane) * 4;
#pragma unroll
                for (int r = 0; r < 4; r++)
                    atomicAdd(&up[base + r], uacc[s][kn][r]);
            }
    }
    __threadfence();
    __syncthreads();
    if (t == 0) winflag = atomicAdd((int*)(wsb + OFF_CTR) + j, 1);
    __syncthreads();
    if (winflag == 0) return;     // first-finishing half exits; winner does epilogue
    __threadfence();

    // reload combined U
#pragma unroll
    for (int s = 0; s < 2; s++)
#pragma unroll
        for (int kn = 0; kn < 4; kn++)
            uacc[s][kn] = *(const v4f*)&Uws[(unsigned)j * 16384u + (((s * 8 + w) * 4 + kn) * 64 + lane) * 4];

    // ---------------- epilogue: l2norm(U) -> M = Wout @ Un -> out = M @ V ----------
#pragma unroll
    for (int s = 0; s < 2; s++) {
        __syncthreads();
#pragma unroll
        for (int kn = 0; kn < 4; kn++)
#pragma unroll
            for (int r = 0; r < 4; r++)
                UF[(kn * 16 + lmod) * 133 + w * 16 + lquad * 4 + r] = uacc[s][kn][r];
        __syncthreads();
        if (t < 64) {
            const float* rp = &UF[t * 133];
            float ss = 0.f;
#pragma unroll 8
            for (int c = 0; c < 128; c++) ss += rp[c] * rp[c];
            UF[t * 133 + 128] = 1.f / (1e-6f + sqrtf(ss));
        }
        __syncthreads();
        {
            int kk = t >> 3, c0 = (t & 7) * 16;
            float rn = UF[kk * 133 + 128];
#pragma unroll
            for (int i = 0; i < 16; i++)
                UH[kk * 136 + c0 + i] = f2bf(UF[kk * 133 + c0 + i] * rn);
        }
        __syncthreads();
        v4f macc[4];
#pragma unroll
        for (int kn = 0; kn < 4; kn++) macc[kn] = (v4f){0.f, 0.f, 0.f, 0.f};
#pragma unroll
        for (int kc = 0; kc < 4; kc++) {
            short8 a = *(const short8*)&wof[(((s * 8 + w) * 4 + kc) * 64 + lane) * 8];
#pragma unroll
            for (int kn = 0; kn < 4; kn++) {
                short8 bb = *(const short8*)&UH[(kn * 16 + lmod) * 136 + kc * 32 + lquad * 8];
                macc[kn] = mfma16(a, bb, macc[kn]);
            }
        }
        __syncthreads();
#pragma unroll
        for (int kn = 0; kn < 4; kn++)
#pragma unroll
            for (int r = 0; r < 4; r++)
                MB[(w * 16 + lquad * 4 + r) * 72 + kn * 16 + lmod] = f2bf(macc[kn][r]);
        __syncthreads();
        // ---- out-GEMM for this s: out_tile = M @ V, operand-swapped MFMA ----
        short8 mfrag[2];
#pragma unroll
        for (int kc = 0; kc < 2; kc++)
            mfrag[kc] = *(const short8*)&MB[(w * 16 + lmod) * 72 + kc * 32 + lquad * 8];
        const long orow = (long)b * C_ * HW_ + (long)(i0 * 32) * W_ + i2 * 32
                        + (long)(w * 16 + lmod) * HW_ + (long)s * B_ * C_ * HW_;
#pragma unroll 4
        for (int ln = 0; ln < 64; ln++) {
            int l = ln * 16 + lmod;                               // V-frag row (A-operand)
            short8 b0  = *(const short8*)&vws[((unsigned long long)j * 1024 + l) * 64 + lquad * 8];
            short8 b1v = *(const short8*)&vws[((unsigned long long)j * 1024 + l) * 64 + 32 + lquad * 8];
            int lo = ln * 16 + lquad * 4;                         // first l of this lane's acc
            v4f acc = {0.f, 0.f, 0.f, 0.f};
            acc = mfma16(b0,  mfrag[0], acc);
            acc = mfma16(b1v, mfrag[1], acc);
            *(v4f*)&out[orow + (long)(lo >> 5) * W_ + (lo & 31)] = acc;
        }
    }
}

extern "C" void kernel_launch(void* const* d_in, const int* in_sizes, int n_in,
                              void* d_out, int out_size, void* d_ws, size_t ws_size,
                              hipStream_t stream) {
    (void)in_sizes; (void)n_in; (void)out_size; (void)ws_size;
    const float* x1    = (const float*)d_in[0];
    const float* x2    = (const float*)d_in[1];
    const float* w_v   = (const float*)d_in[2];
    const float* b_v   = (const float*)d_in[3];
    const float* w1_1  = (const float*)d_in[4];
    const float* b1_1  = (const float*)d_in[5];
    const float* w2_1  = (const float*)d_in[6];
    const float* b2_1  = (const float*)d_in[7];
    const float* wout1 = (const float*)d_in[8];
    const float* w1_2  = (const float*)d_in[9];
    const float* b1_2  = (const float*)d_in[10];
    const float* w2_2  = (const float*)d_in[11];
    const float* b2_2  = (const float*)d_in[12];
    const float* wout2 = (const float*)d_in[13];
    char* wsb  = (char*)d_ws;
    float* out = (float*)d_out;

    hipLaunchKernelGGL(prep_kernel, dim3(400), dim3(256), 0, stream,
                       w_v, b_v, w1_1, b1_1, w2_1, b2_1, wout1,
                       w1_2, b1_2, w2_2, b2_2, wout2, wsb);
    hipLaunchKernelGGL(fused_kernel, dim3(512), dim3(512), 0, stream, x1, x2, wsb, out);
}

// Round 4
// 642.501 us; speedup vs baseline: 1.6610x; 1.6610x over previous
//
#include <hip/hip_runtime.h>
#include <cstdint>

typedef __attribute__((ext_vector_type(8))) short short8;
typedef __attribute__((ext_vector_type(4))) float v4f;

#define B_ 4
#define C_ 128
#define K_ 64
#define H_ 256
#define W_ 256
#define HW_ (H_*W_)
#define L_ 1024
#define J_ 256
#define NCH 16   // 64-l chunks per block (full j per block)

// ws byte offsets
#define OFF_WFH  0ull
#define OFF_WFL  131072ull
#define OFF_WOF  262144ull
#define OFF_BIAS 327680ull
#define OFF_VWS  335872ull

static __device__ __forceinline__ unsigned short f2bf(float x) {
    unsigned u = __builtin_bit_cast(unsigned, x);
    unsigned r = (u + 0x7FFFu + ((u >> 16) & 1u)) >> 16;
    return (unsigned short)r;
}
static __device__ __forceinline__ float bf2f(unsigned short h) {
    unsigned u = ((unsigned)h) << 16;
    return __builtin_bit_cast(float, u);
}
static __device__ __forceinline__ v4f mfma16(short8 a, short8 b, v4f c) {
    return __builtin_amdgcn_mfma_f32_16x16x32_bf16(a, b, c, 0, 0, 0);
}

union U8 { unsigned short u[8]; short8 v; };

// ---------------- prep: pack weights into MFMA A-fragment order ----------------
__global__ void prep_kernel(const float* __restrict__ w_v, const float* __restrict__ b_v,
                            const float* __restrict__ w1_1, const float* __restrict__ b1_1,
                            const float* __restrict__ w2_1, const float* __restrict__ b2_1,
                            const float* __restrict__ wout1,
                            const float* __restrict__ w1_2, const float* __restrict__ b1_2,
                            const float* __restrict__ w2_2, const float* __restrict__ b2_2,
                            const float* __restrict__ wout2,
                            char* __restrict__ wsb) {
    int tid = blockIdx.x * 256 + threadIdx.x;
    if (tid < 65536) {
        // proj weights: [s][omt 16][kc 4][lane 64][jj 8], rows o: w1(128), w2(64), wv-half(64)
        int jj = tid & 7, lane = (tid >> 3) & 63, kc = (tid >> 9) & 3;
        int omt = (tid >> 11) & 15, s = (tid >> 15) & 1;
        int o = omt * 16 + (lane & 15);
        int c = kc * 32 + ((lane >> 4) * 8) + jj;
        const float* w1 = s ? w1_2 : w1_1;
        const float* w2 = s ? w2_2 : w2_1;
        float v;
        if (o < 128)      v = w1[o * 128 + c];
        else if (o < 192) v = w2[(o - 128) * 128 + c];
        else              v = w_v[(o - 192) * 256 + s * 128 + c];
        unsigned short hi = f2bf(v);
        unsigned short lo = f2bf(v - bf2f(hi));
        ((unsigned short*)(wsb + OFF_WFH))[tid] = hi;
        ((unsigned short*)(wsb + OFF_WFL))[tid] = lo;
    } else if (tid < 98304) {
        int id = tid - 65536;
        int jj = id & 7, lane = (id >> 3) & 63, kc = (id >> 9) & 3;
        int om = (id >> 11) & 7, s = (id >> 14) & 1;
        int o = om * 16 + (lane & 15);
        int c = kc * 32 + ((lane >> 4) * 8) + jj;
        const float* wo = s ? wout2 : wout1;
        ((unsigned short*)(wsb + OFF_WOF))[id] = f2bf(wo[o * 128 + c]);
    } else if (tid < 98816) {
        int id = tid - 98304;
        int s = id >> 8, o = id & 255;
        const float* b1 = s ? b1_2 : b1_1;
        const float* b2 = s ? b2_2 : b2_1;
        float v;
        if (o < 128)      v = b1[o];
        else if (o < 192) v = b2[o - 128];
        else              v = b_v[o - 192];
        ((float*)(wsb + OFF_BIAS))[id] = v;
    }
}

// ---------------- fused per-j kernel (proj + U + softmax/V + l2norm + M + out) ----
// 64-l chunks -> 77 KB LDS -> 2 blocks/CU at VGPR<=128.
// waves 0-3: Y1 rows (c 0..127); waves 4-5: Y2 rows (k 0..63); waves 6-7: V logits
__global__ __attribute__((amdgpu_flat_work_group_size(512, 512), amdgpu_waves_per_eu(2, 2)))
void fused_kernel(
    const float* __restrict__ x1, const float* __restrict__ x2,
    char* __restrict__ wsb, float* __restrict__ out) {
    // LDS 77056 B
    __shared__ __align__(16) char smem[77056];
    unsigned short* Xfh = (unsigned short*)&smem[0];       // [ln4][kc4][lane64][8]
    unsigned short* Xfl = (unsigned short*)&smem[16384];
    unsigned short* Y1b = (unsigned short*)&smem[32768];   // [128 c][72 l] bf16
    unsigned short* Y2b = (unsigned short*)&smem[51200];   // [64 k][72 l] bf16
    float*          LG  = (float*)&smem[60416];            // [64 l][65 k] fp32
    float*          UF  = (float*)&smem[0];                // [64 k][133 c] fp32 (epilogue)
    unsigned short* UH  = (unsigned short*)&smem[51200];   // [64 k][136 c] bf16 (epilogue)
    unsigned short* MB  = (unsigned short*)&smem[0];       // [128 o][72 k] bf16 (epilogue)

    const unsigned short* wfh = (const unsigned short*)(wsb + OFF_WFH);
    const unsigned short* wfl = (const unsigned short*)(wsb + OFF_WFL);
    const unsigned short* wof = (const unsigned short*)(wsb + OFF_WOF);
    const float* biasws = (const float*)(wsb + OFF_BIAS);
    unsigned short* vws = (unsigned short*)(wsb + OFF_VWS);

    const int t = threadIdx.x;
    const int lane = t & 63;
    const int w = __builtin_amdgcn_readfirstlane(t >> 6);
    const int j = blockIdx.x;
    const int b = j >> 6, q = j & 63, i0 = q >> 3, i2 = q & 7;
    const long imgbase = (long)b * C_ * HW_ + (long)(i0 * 32) * W_ + i2 * 32;

    const int lquad = lane >> 4;        // 0..3
    const int lmod = lane & 15;

    // biases per lane (rows o = w*32 + h*16 + lquad*4 + r)
    float pb[2][2][4];
#pragma unroll
    for (int s = 0; s < 2; s++)
#pragma unroll
        for (int h = 0; h < 2; h++)
#pragma unroll
            for (int r = 0; r < 4; r++)
                pb[s][h][r] = biasws[s * 256 + w * 32 + h * 16 + lquad * 4 + r];

    v4f uacc[2][4];
#pragma unroll
    for (int s = 0; s < 2; s++)
#pragma unroll
        for (int kn = 0; kn < 4; kn++)
            uacc[s][kn] = (v4f){0.f, 0.f, 0.f, 0.f};

    // staging decode: thread t stages l-column ll, c-octets {cw, cw+8}
    const int ll = t & 63;              // l within 64-chunk
    const int cw = t >> 6;              // 0..7
    const int lgrp = ll >> 4, lp = ll & 15;

    // prefetch first chunk (lc=0, s=0) into registers
    float R[16];
#pragma unroll
    for (int p = 0; p < 2; p++)
#pragma unroll
        for (int jj = 0; jj < 8; jj++) {
            int c = (p * 8 + cw) * 8 + jj;
            R[p * 8 + jj] = x1[imgbase + (long)c * HW_ + (ll >> 5) * W_ + (ll & 31)];
        }

    for (int lc = 0; lc < NCH; lc++) {
        v4f pacc[2][4];
#pragma unroll
        for (int s = 0; s < 2; s++) {
            // ---- convert prefetched R (fp32 -> bf16 hi/lo, B-frag order) into LDS ----
#pragma unroll
            for (int p = 0; p < 2; p++) {
                U8 hv, lv;
#pragma unroll
                for (int jj = 0; jj < 8; jj++) {
                    float v = R[p * 8 + jj];
                    unsigned short hh = f2bf(v);
                    hv.u[jj] = hh;
                    lv.u[jj] = f2bf(v - bf2f(hh));
                }
                int co = p * 8 + cw;
                int base = ((lgrp * 4 + (co >> 2)) * 64 + ((co & 3) * 16 + lp)) * 8;
                *(short8*)&Xfh[base] = hv.v;
                *(short8*)&Xfl[base] = lv.v;
            }
            __syncthreads();
            // ---- issue next-stage x loads; they ride under the MFMA phase ----
            if (s == 0 || lc < NCH - 1) {
                const float* xp = s ? x1 : x2;
                const int nrow = (s ? (lc + 1) : lc) * 2 + (ll >> 5);
#pragma unroll
                for (int p = 0; p < 2; p++)
#pragma unroll
                    for (int jj = 0; jj < 8; jj++) {
                        int c = (p * 8 + cw) * 8 + jj;
                        R[p * 8 + jj] = xp[imgbase + (long)c * HW_ + (long)nrow * W_ + (ll & 31)];
                    }
            }
            // ---- projection MFMAs (split-3: Whi*Xhi + Wlo*Xhi + Whi*Xlo) ----
            if (s == 0 || w < 6) {
#pragma unroll
                for (int h = 0; h < 2; h++)
#pragma unroll
                    for (int ln = 0; ln < 4; ln++)
                        pacc[h][ln] = (v4f){pb[s][h][0], pb[s][h][1], pb[s][h][2], pb[s][h][3]};
            }
#pragma unroll
            for (int kc = 0; kc < 4; kc++) {
                int wi0 = (((s * 16 + (w * 2 + 0)) * 4 + kc) * 64 + lane) * 8;
                int wi1 = (((s * 16 + (w * 2 + 1)) * 4 + kc) * 64 + lane) * 8;
                short8 wh0 = *(const short8*)&wfh[wi0];
                short8 wh1 = *(const short8*)&wfh[wi1];
                short8 wlo0 = *(const short8*)&wfl[wi0];
                short8 wlo1 = *(const short8*)&wfl[wi1];
#pragma unroll
                for (int ln = 0; ln < 4; ln++) {
                    short8 bh = *(const short8*)&Xfh[((ln * 4 + kc) * 64 + lane) * 8];
                    short8 bl = *(const short8*)&Xfl[((ln * 4 + kc) * 64 + lane) * 8];
                    pacc[0][ln] = mfma16(wh0, bh, pacc[0][ln]);
                    pacc[0][ln] = mfma16(wlo0, bh, pacc[0][ln]);
                    pacc[0][ln] = mfma16(wh0, bl, pacc[0][ln]);
                    pacc[1][ln] = mfma16(wh1, bh, pacc[1][ln]);
                    pacc[1][ln] = mfma16(wlo1, bh, pacc[1][ln]);
                    pacc[1][ln] = mfma16(wh1, bl, pacc[1][ln]);
                }
            }
            // ---- write Y / logits ----
            if (w < 4) {
#pragma unroll
                for (int h = 0; h < 2; h++)
#pragma unroll
                    for (int ln = 0; ln < 4; ln++)
#pragma unroll
                        for (int r = 0; r < 4; r++)
                            Y1b[(w * 32 + h * 16 + lquad * 4 + r) * 72 + ln * 16 + lmod] = f2bf(pacc[h][ln][r]);
            } else if (w < 6) {
#pragma unroll
                for (int h = 0; h < 2; h++)
#pragma unroll
                    for (int ln = 0; ln < 4; ln++)
#pragma unroll
                        for (int r = 0; r < 4; r++)
                            Y2b[((w - 4) * 32 + h * 16 + lquad * 4 + r) * 72 + ln * 16 + lmod] = f2bf(pacc[h][ln][r]);
            } else if (s == 1) {
#pragma unroll
                for (int h = 0; h < 2; h++)
#pragma unroll
                    for (int ln = 0; ln < 4; ln++)
#pragma unroll
                        for (int r = 0; r < 4; r++)
                            LG[(ln * 16 + lmod) * 65 + (w - 6) * 32 + h * 16 + lquad * 4 + r] = pacc[h][ln][r];
            }
            __syncthreads();
            // ---- U-MFMA: U_s += Y1 @ Y2^T over this 64-l chunk ----
#pragma unroll
            for (int kcl = 0; kcl < 2; kcl++) {
                short8 a = *(const short8*)&Y1b[(w * 16 + lmod) * 72 + kcl * 32 + lquad * 8];
#pragma unroll
                for (int kn = 0; kn < 4; kn++) {
                    short8 bb = *(const short8*)&Y2b[(kn * 16 + lmod) * 72 + kcl * 32 + lquad * 8];
                    uacc[s][kn] = mfma16(a, bb, uacc[s][kn]);
                }
            }
            if (s == 1) {
                // ---- wave-parallel softmax + direct V store (all 512 threads) ----
                // 8 threads per l-column: part = t&7 owns k in [part*8, part*8+8)
                int l2 = t >> 3, part = t & 7;
                float vv[8];
#pragma unroll
                for (int i = 0; i < 8; i++) vv[i] = LG[l2 * 65 + part * 8 + i];
                float mx = vv[0];
#pragma unroll
                for (int i = 1; i < 8; i++) mx = fmaxf(mx, vv[i]);
                mx = fmaxf(mx, __shfl_xor(mx, 1));
                mx = fmaxf(mx, __shfl_xor(mx, 2));
                mx = fmaxf(mx, __shfl_xor(mx, 4));
                float ssum = 0.f;
#pragma unroll
                for (int i = 0; i < 8; i++) { float e = __expf(vv[i] - mx); vv[i] = e; ssum += e; }
                ssum += __shfl_xor(ssum, 1);
                ssum += __shfl_xor(ssum, 2);
                ssum += __shfl_xor(ssum, 4);
                float rs = 1.f / ssum;
                U8 o1;
#pragma unroll
                for (int i = 0; i < 8; i++) o1.u[i] = f2bf(vv[i] * rs);
                unsigned long long vb = ((unsigned long long)j * 1024 + lc * 64 + l2) * 64 + part * 8;
                *(short8*)&vws[vb] = o1.v;
            }
        }
    }

    // make this block's V stores visible to its own reads
    __threadfence();

    // ---------------- epilogue: l2norm(U) -> M = Wout @ Un -> out = M @ V ----------
#pragma unroll
    for (int s = 0; s < 2; s++) {
        __syncthreads();
#pragma unroll
        for (int kn = 0; kn < 4; kn++)
#pragma unroll
            for (int r = 0; r < 4; r++)
                UF[(kn * 16 + lmod) * 133 + w * 16 + lquad * 4 + r] = uacc[s][kn][r];
        __syncthreads();
        if (t < 64) {
            const float* rp = &UF[t * 133];
            float ss = 0.f;
#pragma unroll 8
            for (int c = 0; c < 128; c++) ss += rp[c] * rp[c];
            UF[t * 133 + 128] = 1.f / (1e-6f + sqrtf(ss));
        }
        __syncthreads();
        {
            int kk = t >> 3, c0 = (t & 7) * 16;
            float rn = UF[kk * 133 + 128];
#pragma unroll
            for (int i = 0; i < 16; i++)
                UH[kk * 136 + c0 + i] = f2bf(UF[kk * 133 + c0 + i] * rn);
        }
        __syncthreads();
        v4f macc[4];
#pragma unroll
        for (int kn = 0; kn < 4; kn++) macc[kn] = (v4f){0.f, 0.f, 0.f, 0.f};
#pragma unroll
        for (int kc = 0; kc < 4; kc++) {
            short8 a = *(const short8*)&wof[(((s * 8 + w) * 4 + kc) * 64 + lane) * 8];
#pragma unroll
            for (int kn = 0; kn < 4; kn++) {
                short8 bb = *(const short8*)&UH[(kn * 16 + lmod) * 136 + kc * 32 + lquad * 8];
                macc[kn] = mfma16(a, bb, macc[kn]);
            }
        }
        __syncthreads();
#pragma unroll
        for (int kn = 0; kn < 4; kn++)
#pragma unroll
            for (int r = 0; r < 4; r++)
                MB[(w * 16 + lquad * 4 + r) * 72 + kn * 16 + lmod] = f2bf(macc[kn][r]);
        __syncthreads();
        // ---- out-GEMM for this s: out_tile = M @ V, operand-swapped MFMA ----
        short8 mfrag[2];
#pragma unroll
        for (int kc = 0; kc < 2; kc++)
            mfrag[kc] = *(const short8*)&MB[(w * 16 + lmod) * 72 + kc * 32 + lquad * 8];
        const long orow = (long)b * C_ * HW_ + (long)(i0 * 32) * W_ + i2 * 32
                        + (long)(w * 16 + lmod) * HW_ + (long)s * B_ * C_ * HW_;
#pragma unroll 4
        for (int ln = 0; ln < 64; ln++) {
            int l = ln * 16 + lmod;                               // V-frag row (A-operand)
            short8 b0  = *(const short8*)&vws[((unsigned long long)j * 1024 + l) * 64 + lquad * 8];
            short8 b1v = *(const short8*)&vws[((unsigned long long)j * 1024 + l) * 64 + 32 + lquad * 8];
            int lo = ln * 16 + lquad * 4;                         // first l of this lane's acc
            v4f acc = {0.f, 0.f, 0.f, 0.f};
            acc = mfma16(b0,  mfrag[0], acc);
            acc = mfma16(b1v, mfrag[1], acc);
            *(v4f*)&out[orow + (long)(lo >> 5) * W_ + (lo & 31)] = acc;
        }
    }
}

extern "C" void kernel_launch(void* const* d_in, const int* in_sizes, int n_in,
                              void* d_out, int out_size, void* d_ws, size_t ws_size,
                              hipStream_t stream) {
    (void)in_sizes; (void)n_in; (void)out_size; (void)ws_size;
    const float* x1    = (const float*)d_in[0];
    const float* x2    = (const float*)d_in[1];
    const float* w_v   = (const float*)d_in[2];
    const float* b_v   = (const float*)d_in[3];
    const float* w1_1  = (const float*)d_in[4];
    const float* b1_1  = (const float*)d_in[5];
    const float* w2_1  = (const float*)d_in[6];
    const float* b2_1  = (const float*)d_in[7];
    const float* wout1 = (const float*)d_in[8];
    const float* w1_2  = (const float*)d_in[9];
    const float* b1_2  = (const float*)d_in[10];
    const float* w2_2  = (const float*)d_in[11];
    const float* b2_2  = (const float*)d_in[12];
    const float* wout2 = (const float*)d_in[13];
    char* wsb  = (char*)d_ws;
    float* out = (float*)d_out;

    hipLaunchKernelGGL(prep_kernel, dim3(386), dim3(256), 0, stream,
                       w_v, b_v, w1_1, b1_1, w2_1, b2_1, wout1,
                       w1_2, b1_2, w2_2, b2_2, wout2, wsb);
    hipLaunchKernelGGL(fused_kernel, dim3(J_), dim3(512), 0, stream, x1, x2, wsb, out);
}